// Round 5
// baseline (22389.073 us; speedup 1.0000x reference)
//
#include <hip/hip_runtime.h>

typedef unsigned short u16;
typedef __attribute__((ext_vector_type(8))) short bf16x8;
typedef __attribute__((ext_vector_type(4))) float f32x4;

#define MFMA(a,b,c) __builtin_amdgcn_mfma_f32_16x16x32_bf16(a,b,c,0,0,0)

#define B_   128
#define T_   200
#define F_   171
#define FX_  256          // padded frame (8 K-chunks of 32; zero-padded weights)
#define H_   1024
#define G_   4096
#define TF_  (T_*F_)
#define BH_  (B_*H_)
#define NB_  512
#define NT_  512          // 8 waves; 2 blocks/CU -> 16 waves/CU

__device__ __forceinline__ u16 f2bf(float v){
  union { float f; unsigned u; } c; c.f = v;
  unsigned r = (c.u + 0x7fffu + ((c.u >> 16) & 1u)) >> 16;   // RNE
  return (u16)r;
}
__device__ __forceinline__ float bf2f(u16 h){
  union { unsigned u; float f; } c; c.u = ((unsigned)h) << 16; return c.f;
}
__device__ __forceinline__ bf16x8 ld8(const u16* p){
  return *reinterpret_cast<const bf16x8*>(p);
}
__device__ __forceinline__ float sigm(float v){ return 1.f / (1.f + __expf(-v)); }

// ---------- group barrier (64 blocks = one 16-batch group) ----------
// FAST (group co-resident on one XCD): no fences — stores drain at __syncthreads,
// land in the shared XCD L2; consumers' plain loads hit that L2.
// SLOW (mapping check failed): fenced protocol (release-wb / acquire-inv).
__device__ __forceinline__ void group_bar(unsigned* gcnt, unsigned tgt, int tid, bool fast){
  __syncthreads();
  if (tid == 0){
    if (!fast) __builtin_amdgcn_fence(__ATOMIC_RELEASE, "agent");
    __hip_atomic_fetch_add(gcnt, 1u, __ATOMIC_RELAXED, __HIP_MEMORY_SCOPE_AGENT);
    while (__hip_atomic_load(gcnt, __ATOMIC_RELAXED, __HIP_MEMORY_SCOPE_AGENT) < tgt)
      __builtin_amdgcn_s_sleep(1);
    if (!fast) __builtin_amdgcn_fence(__ATOMIC_ACQUIRE, "agent");
  }
  asm volatile("" ::: "memory");
  __syncthreads();
}

// ---------- K-slice GEMM: KC chunks of 32, 4 col-tiles, 2-deep prefetch ----------
template<int KC, int KS>
__device__ __forceinline__ void gemm(const u16* __restrict__ Wb,
                                     const u16* __restrict__ Ah, const u16* __restrict__ Al,
                                     f32x4 (&acc)[4])
{
  bf16x8 pa[2], pl[2], pw[2][4];
  auto LD = [&](int kc, int s){
    pa[s] = ld8(Ah + kc*32);
    pl[s] = ld8(Al + kc*32);
#pragma unroll
    for (int tt = 0; tt < 4; ++tt) pw[s][tt] = ld8(Wb + (size_t)tt*16*KS + kc*32);
  };
  LD(0, 0);
  if (KC > 1) LD(1, 1);
#pragma unroll
  for (int kc = 0; kc < KC; ++kc){
    const int s = kc & 1;
#pragma unroll
    for (int tt = 0; tt < 4; ++tt){
      acc[tt] = MFMA(pa[s], pw[s][tt], acc[tt]);
      acc[tt] = MFMA(pl[s], pw[s][tt], acc[tt]);
    }
    if (kc + 2 < KC) LD(kc + 2, s);
  }
}
__device__ __forceinline__ void zacc(f32x4 (&acc)[4]){
#pragma unroll
  for (int i = 0; i < 4; ++i) acc[i] = (f32x4){0,0,0,0};
}

// ---------- cross-wave K-reduce + cell update (block: 16 batches x 16 units) ----------
__device__ __forceinline__ void reduce_cell(
    f32x4 (&acc)[4],
    const float* __restrict__ bias64, float* __restrict__ c_l,
    u16* __restrict__ ohh, u16* __restrict__ ohl,
    int g, int c, int w, int ke, int r16, int tid, float (*red)[16][69])
{
#pragma unroll
  for (int tt = 0; tt < 4; ++tt){
#pragma unroll
    for (int r = 0; r < 4; ++r)
      red[w][ke*4 + r][tt*16 + r16] = acc[tt][r];   // D: row=ke*4+r, col=lane&15
  }
  __syncthreads();
  if (tid < 256){
    const int bl = tid >> 4, u = tid & 15;
    float gg[4];
#pragma unroll
    for (int q = 0; q < 4; ++q){
      float s = 0.f;
#pragma unroll
      for (int ww = 0; ww < 8; ++ww) s += red[ww][bl][q*16 + u];
      gg[q] = s + bias64[q*16 + u];
    }
    const int idx = (g*16 + bl)*H_ + c*16 + u;
    const float co = c_l[idx];
    const float cn = sigm(gg[1])*co + sigm(gg[0])*tanhf(gg[2]);
    const float hn = sigm(gg[3])*tanhf(cn);
    c_l[idx] = cn;
    const u16 hh = f2bf(hn);
    ohh[idx] = hh;
    ohl[idx] = f2bf(hn - bf2f(hh));
  }
}

// ---------- main persistent kernel: 512 blocks, group g=bid&7 (16 rows), c=bid>>3 ----------
__global__ __launch_bounds__(NT_, 4) void k_main(
    const float* __restrict__ x, float* __restrict__ out,
    const u16* __restrict__ W1X, const u16* __restrict__ W1H,
    const u16* __restrict__ W2,  const u16* __restrict__ W3,
    const u16* __restrict__ WD,
    const float* __restrict__ bperm, const float* __restrict__ bdec,
    u16* __restrict__ h_hi, u16* __restrict__ h_lo, float* __restrict__ cst,
    u16* __restrict__ if_hi, u16* __restrict__ if_lo,
    unsigned* __restrict__ bar)
{
  const int tid = threadIdx.x, bid = blockIdx.x;
  const int g = bid & 7, c = bid >> 3;          // group = batch rows g*16..+16; c = unit-group
  const int w = tid >> 6, lane = tid & 63;      // 8 waves split K
  const int r16 = lane & 15, ke = lane >> 4;
  __shared__ float red[8][16][69];
  unsigned ep = 0;

  // ---- one-time XCD co-residency check ----
  unsigned xcc; asm volatile("s_getreg_b32 %0, hwreg(HW_REG_XCC_ID)" : "=s"(xcc));
  xcc &= 7;
  unsigned* grpcnt = bar + g*64;                 // 256B-spaced per-group counters
  unsigned* root   = bar + 8*64;
  unsigned* chk    = bar + 9*64;                 // 8 groups x 16 xcc buckets
  if (tid == 0){
    __hip_atomic_fetch_add(&chk[g*16 + xcc], 1u, __ATOMIC_RELAXED, __HIP_MEMORY_SCOPE_AGENT);
    __builtin_amdgcn_fence(__ATOMIC_RELEASE, "agent");
    __hip_atomic_fetch_add(root, 1u, __ATOMIC_RELAXED, __HIP_MEMORY_SCOPE_AGENT);
    while (__hip_atomic_load(root, __ATOMIC_RELAXED, __HIP_MEMORY_SCOPE_AGENT) < (unsigned)NB_)
      __builtin_amdgcn_s_sleep(1);
    __builtin_amdgcn_fence(__ATOMIC_ACQUIRE, "agent");
  }
  __syncthreads();
  const bool fast =
    (__hip_atomic_load(&chk[g*16 + xcc], __ATOMIC_RELAXED, __HIP_MEMORY_SCOPE_AGENT) == 64u);

  const size_t wcol = (size_t)(c*64 + r16);
  const u16* w1xB = W1X + wcol*FX_  + w*32  + ke*8;   // K=256,  slice 32/wave
  const u16* w1hB = W1H + wcol*1024 + w*128 + ke*8;   // K=1024, slice 128/wave
  const u16* w2B  = W2  + wcol*2048 + w*256 + ke*8;   // K=2048, slice 256/wave
  const u16* w3B  = W3  + wcol*2048 + w*256 + ke*8;
  const int aRowH = (g*16 + r16)*H_  + ke*8;
  const int aRowX = (g*16 + r16)*FX_ + ke*8;
  const int hsel  = w >> 2;                     // 0: lower-layer half, 1: own-prev half
  const int hq    = (w & 3) * 256;

  f32x4 acc[4];
  zacc(acc);                                    // carried L1-h partial; zero at t=0 (h0=0)

  for (int t = 0; t < T_; ++t){
    const int cur = t & 1, prv = cur ^ 1;

    // ---------- P1: L1 x-part (K=256) on carried h-part partial + cell ----------
    gemm<1, FX_>(w1xB, if_hi + aRowX + w*32, if_lo + aRowX + w*32, acc);
    reduce_cell(acc, bperm + 0*G_ + c*64, cst + 0*BH_,
                h_hi + (0*2+cur)*BH_, h_lo + (0*2+cur)*BH_,
                g, c, w, ke, r16, tid, red);
    ++ep; group_bar(grpcnt, ep*64u, tid, fast);

    // ---------- P2: L2 = [h0_cur | h1_prev], K=2048 ----------
    {
      const u16* ah = (hsel ? h_hi + (1*2+prv)*BH_ : h_hi + (0*2+cur)*BH_) + aRowH + hq;
      const u16* al = (hsel ? h_lo + (1*2+prv)*BH_ : h_lo + (0*2+cur)*BH_) + aRowH + hq;
      zacc(acc);
      gemm<8, 2048>(w2B, ah, al, acc);
      reduce_cell(acc, bperm + 1*G_ + c*64, cst + 1*BH_,
                  h_hi + (1*2+cur)*BH_, h_lo + (1*2+cur)*BH_,
                  g, c, w, ke, r16, tid, red);
    }
    ++ep; group_bar(grpcnt, ep*64u, tid, fast);

    // ---------- P3: L3 = [h1_cur | h2_prev], K=2048 ----------
    {
      const u16* ah = (hsel ? h_hi + (2*2+prv)*BH_ : h_hi + (1*2+cur)*BH_) + aRowH + hq;
      const u16* al = (hsel ? h_lo + (2*2+prv)*BH_ : h_lo + (1*2+cur)*BH_) + aRowH + hq;
      zacc(acc);
      gemm<8, 2048>(w3B, ah, al, acc);
      reduce_cell(acc, bperm + 2*G_ + c*64, cst + 2*BH_,
                  h_hi + (2*2+cur)*BH_, h_lo + (2*2+cur)*BH_,
                  g, c, w, ke, r16, tid, red);
    }
    ++ep; group_bar(grpcnt, ep*64u, tid, fast);

    // ---------- P4: decoder (group's c<11) + L1 h-part precompute for t+1 (all) ----------
    if (c < 11){                                  // 11 col-tiles cover F=171
      const u16* ah = h_hi + (2*2+cur)*BH_ + (g*16 + r16)*H_ + ke*8 + w*128;
      const u16* al = h_lo + (2*2+cur)*BH_ + (g*16 + r16)*H_ + ke*8 + w*128;
      const u16* wd = WD + (size_t)(c*16 + r16)*1024 + w*128 + ke*8;
      f32x4 d0 = {0,0,0,0}, d1 = {0,0,0,0};
#pragma unroll
      for (int kc = 0; kc < 4; ++kc){
        const bf16x8 bw = ld8(wd + kc*32);
        d0 = MFMA(ld8(ah + kc*32), bw, d0);
        d1 = MFMA(ld8(al + kc*32), bw, d1);
      }
#pragma unroll
      for (int r = 0; r < 4; ++r) red[w][ke*4 + r][r16] = d0[r] + d1[r];
      __syncthreads();
      if (tid < 256){
        const int bl = tid >> 4, fl = tid & 15;
        float v = bdec[c*16 + fl];
#pragma unroll
        for (int ww = 0; ww < 8; ++ww) v += red[ww][bl][fl];
        const int f = c*16 + fl, b = g*16 + bl;
        if (f < F_) out[(size_t)b*TF_ + (size_t)t*F_ + f] = v;
        if (t + 1 < T_){
          float in = 0.f;
          if (f < F_){
            const bool gt = (((t+1) % 10) < 5);
            in = gt ? x[(size_t)b*TF_ + (size_t)(t+1)*F_ + f] : v;
          }
          const u16 hh = f2bf(in);
          if_hi[b*FX_ + f] = hh;
          if_lo[b*FX_ + f] = f2bf(in - bf2f(hh));
        }
      }
    }
    zacc(acc);                                    // L1 h-part on h0_cur (= h0_prev of t+1)
    gemm<4, 1024>(w1hB, h_hi + (0*2+cur)*BH_ + aRowH + w*128,
                         h_lo + (0*2+cur)*BH_ + aRowH + w*128, acc);
    ++ep; group_bar(grpcnt, ep*64u, tid, fast);   // acc carries into P1 of t+1
  }
}

// ---------- prep: permuted biases, decoder bias, initial in_frame ----------
__global__ void k_prep(const float* __restrict__ x,
                       const float* bi1, const float* bh1,
                       const float* bi2, const float* bh2,
                       const float* bi3, const float* bh3,
                       const float* bd_in,
                       float* __restrict__ bperm, float* __restrict__ bdec,
                       u16* __restrict__ if_hi, u16* __restrict__ if_lo)
{
  const int i = blockIdx.x * blockDim.x + threadIdx.x;
  if (i < 3*G_){
    const int l = i >> 12, r = i & 4095;
    const int ug = r >> 6, g = (r >> 4) & 3, u = r & 15;
    const int j = (g << 10) | (ug << 4) | u;          // original gate row
    const float* bi = (l == 0) ? bi1 : (l == 1) ? bi2 : bi3;
    const float* bh = (l == 0) ? bh1 : (l == 1) ? bh2 : bh3;
    bperm[i] = bi[j] + bh[j];
  }
  const int i2 = i - 3*G_;
  if (i2 >= 0 && i2 < 192) bdec[i2] = (i2 < F_) ? bd_in[i2] : 0.f;
  const int i3 = i2 - 192;
  if (i3 >= 0 && i3 < B_*FX_){
    const int b = i3 >> 8, f = i3 & 255;
    const float v = (f < F_) ? x[(size_t)b*TF_ + f] : 0.f;   // t=0 is ground-truth
    const u16 hh = f2bf(v);
    if_hi[i3] = hh;
    if_lo[i3] = f2bf(v - bf2f(hh));
  }
}

// ---------- weight convert: fp32 -> bf16, gate-permuted ----------
__global__ void k_wcvt(const float* __restrict__ Wih1, const float* __restrict__ Whh1,
                       const float* __restrict__ Wih2, const float* __restrict__ Whh2,
                       const float* __restrict__ Wih3, const float* __restrict__ Whh3,
                       const float* __restrict__ Wd_in,
                       u16* __restrict__ W1X, u16* __restrict__ W1H,
                       u16* __restrict__ W2,  u16* __restrict__ W3,
                       u16* __restrict__ WD)
{
  const int region = blockIdx.y;
  const size_t stride = (size_t)gridDim.x * blockDim.x;
  const size_t i0 = (size_t)blockIdx.x * blockDim.x + threadIdx.x;
  if (region == 0){
    for (size_t i = i0; i < (size_t)G_*FX_; i += stride){
      const int r = (int)(i >> 8), k = (int)(i & 255);
      const int ug = r >> 6, g = (r >> 4) & 3, u = r & 15;
      const int j = (g << 10) | (ug << 4) | u;
      W1X[i] = f2bf((k < F_) ? Wih1[(size_t)j*F_ + k] : 0.f);
    }
  } else if (region == 1){
    for (size_t i = i0; i < (size_t)G_*H_; i += stride){
      const int r = (int)(i >> 10), k = (int)(i & 1023);
      const int ug = r >> 6, g = (r >> 4) & 3, u = r & 15;
      const int j = (g << 10) | (ug << 4) | u;
      W1H[i] = f2bf(Whh1[(size_t)j*H_ + k]);
    }
  } else if (region == 2){
    for (size_t i = i0; i < (size_t)G_*2048; i += stride){
      const int r = (int)(i >> 11), k = (int)(i & 2047);
      const int ug = r >> 6, g = (r >> 4) & 3, u = r & 15;
      const int j = (g << 10) | (ug << 4) | u;
      W2[i] = f2bf((k < H_) ? Wih2[(size_t)j*H_ + k] : Whh2[(size_t)j*H_ + (k - H_)]);
    }
  } else if (region == 3){
    for (size_t i = i0; i < (size_t)G_*2048; i += stride){
      const int r = (int)(i >> 11), k = (int)(i & 2047);
      const int ug = r >> 6, g = (r >> 4) & 3, u = r & 15;
      const int j = (g << 10) | (ug << 4) | u;
      W3[i] = f2bf((k < H_) ? Wih3[(size_t)j*H_ + k] : Whh3[(size_t)j*H_ + (k - H_)]);
    }
  } else {
    for (size_t i = i0; i < (size_t)176*H_; i += stride){
      const int r = (int)(i >> 10), k = (int)(i & 1023);
      WD[i] = f2bf((r < F_) ? Wd_in[(size_t)r*H_ + k] : 0.f);
    }
  }
}

extern "C" void kernel_launch(void* const* d_in, const int* in_sizes, int n_in,
                              void* d_out, int out_size, void* d_ws, size_t ws_size,
                              hipStream_t stream)
{
  const float* x    = (const float*)d_in[0];
  const float* Wih1 = (const float*)d_in[1];
  const float* bih1 = (const float*)d_in[2];
  const float* Whh1 = (const float*)d_in[3];
  const float* bhh1 = (const float*)d_in[4];
  const float* Wih2 = (const float*)d_in[5];
  const float* bih2 = (const float*)d_in[6];
  const float* Whh2 = (const float*)d_in[7];
  const float* bhh2 = (const float*)d_in[8];
  const float* Wih3 = (const float*)d_in[9];
  const float* bih3 = (const float*)d_in[10];
  const float* Whh3 = (const float*)d_in[11];
  const float* bhh3 = (const float*)d_in[12];
  const float* Wdec = (const float*)d_in[13];
  const float* bdec_in = (const float*)d_in[14];
  float* out = (float*)d_out;

  char* ws = (char*)d_ws;
  size_t off = 0;
  auto alloc = [&](size_t bytes) -> void* {
    void* p = ws + off;
    off = (off + bytes + 255) & ~(size_t)255;
    return p;
  };
  unsigned* bar = (unsigned*)alloc(8192);        // group counters + root + chk buckets
  u16* h_hi  = (u16*)alloc((size_t)3*2*BH_*2);
  u16* h_lo  = (u16*)alloc((size_t)3*2*BH_*2);
  float* cst = (float*)alloc((size_t)3*BH_*4);
  u16* if_hi = (u16*)alloc((size_t)B_*FX_*2);
  u16* if_lo = (u16*)alloc((size_t)B_*FX_*2);
  const size_t zero_bytes = off;                 // state zone: re-zeroed every launch
  u16* W1X = (u16*)alloc((size_t)G_*FX_*2);
  u16* W1H = (u16*)alloc((size_t)G_*H_*2);
  u16* W2  = (u16*)alloc((size_t)G_*2048*2);
  u16* W3  = (u16*)alloc((size_t)G_*2048*2);
  u16* WD  = (u16*)alloc((size_t)176*H_*2);
  float* bperm = (float*)alloc((size_t)3*G_*4);
  float* bdec  = (float*)alloc((size_t)192*4);

  hipMemsetAsync(d_ws, 0, zero_bytes, stream);
  k_prep<<<180, 256, 0, stream>>>(x, bih1, bhh1, bih2, bhh2, bih3, bhh3, bdec_in,
                                  bperm, bdec, if_hi, if_lo);
  k_wcvt<<<dim3(2048, 5), 256, 0, stream>>>(Wih1, Whh1, Wih2, Whh2, Wih3, Whh3, Wdec,
                                            W1X, W1H, W2, W3, WD);
  k_main<<<NB_, NT_, 0, stream>>>(x, out, W1X, W1H, W2, W3, WD, bperm, bdec,
                                  h_hi, h_lo, cst, if_hi, if_lo, bar);
}